// Round 4
// baseline (1180.836 us; speedup 1.0000x reference)
//
#include <hip/hip_runtime.h>
#include <stdint.h>

typedef __attribute__((ext_vector_type(8))) __bf16 bf16x8;
typedef __attribute__((ext_vector_type(4))) float  f32x4;

// ---------- helpers ----------
__device__ __forceinline__ uint16_t f2b(float f) {           // fp32 -> bf16 RNE
  uint32_t u = __float_as_uint(f);
  u += 0x7fffu + ((u >> 16) & 1u);
  return (uint16_t)(u >> 16);
}
__device__ __forceinline__ float b2f_lo(uint32_t p) { return __uint_as_float(p << 16); }
__device__ __forceinline__ float b2f_hi(uint32_t p) { return __uint_as_float(p & 0xffff0000u); }

// branch-free tanh: 1 - 2/(e^{2x}+1); saturates correctly at +-1
__device__ __forceinline__ float tanh_fast(float x) {
  float e = __expf(2.0f * x);
  return 1.0f - 2.0f / (e + 1.0f);
}

// barrier that drains ONLY lgkmcnt (ds ops), leaving global prefetch loads in
// flight across the barrier. "memory" clobber stops compile-time reordering.
__device__ __forceinline__ void barrier_lgkm() {
  asm volatile("s_waitcnt lgkmcnt(0)\n\ts_barrier" ::: "memory");
}

// ---------- 1. encoder fp32 -> bf16 (8 elems/thread) ----------
__global__ __launch_bounds__(256) void convert_enc(const float4* __restrict__ in,
                                                   uint4* __restrict__ out) {
  int i = blockIdx.x * 256 + threadIdx.x;
  float4 a = in[2 * i], b = in[2 * i + 1];
  uint4 o;
  o.x = (uint32_t)f2b(a.x) | ((uint32_t)f2b(a.y) << 16);
  o.y = (uint32_t)f2b(a.z) | ((uint32_t)f2b(a.w) << 16);
  o.z = (uint32_t)f2b(b.x) | ((uint32_t)f2b(b.y) << 16);
  o.w = (uint32_t)f2b(b.z) | ((uint32_t)f2b(b.w) << 16);
  out[i] = o;
}

// ---------- 2. W_a (K x N) -> WT bf16 (N x K), LDS-tiled transpose ----------
__global__ __launch_bounds__(256) void convert_WT(const float* __restrict__ W,
                                                  uint16_t* __restrict__ WT) {
  __shared__ float tile[64][65];
  int k0 = (blockIdx.x & 15) * 64;
  int n0 = (blockIdx.x >> 4) * 64;
  #pragma unroll
  for (int it = 0; it < 16; ++it) {
    int idx = it * 256 + threadIdx.x;
    int kr = idx >> 6, nc = idx & 63;
    tile[kr][nc] = W[(size_t)(k0 + kr) * 1024 + n0 + nc];
  }
  __syncthreads();
  #pragma unroll
  for (int it = 0; it < 16; ++it) {
    int idx = it * 256 + threadIdx.x;
    int nr = idx >> 6, kc = idx & 63;
    WT[(size_t)(n0 + nr) * 1024 + k0 + kc] = f2b(tile[kc][nr]);
  }
}

// ---------- 3. u[b,f] += sum_{d in seg} dec_last[b,d] * U[d,f]  (fp32, atomic) ----
__global__ __launch_bounds__(256) void compute_u(const float* __restrict__ dec,
                                                 const float4* __restrict__ U4,
                                                 float* __restrict__ u) {
  int b = blockIdx.x >> 3, dseg = blockIdx.x & 7;
  __shared__ float sdec[128];
  if (threadIdx.x < 128)
    sdec[threadIdx.x] = dec[(size_t)b * 64 * 1024 + 63 * 1024 + dseg * 128 + threadIdx.x];
  __syncthreads();
  float4 a = {0.f, 0.f, 0.f, 0.f};
  const float4* Ub = U4 + (size_t)dseg * 128 * 256 + threadIdx.x;
  #pragma unroll 4
  for (int d = 0; d < 128; ++d) {
    float4 w = Ub[(size_t)d * 256];
    float s = sdec[d];
    a.x = fmaf(s, w.x, a.x);
    a.y = fmaf(s, w.y, a.y);
    a.z = fmaf(s, w.z, a.z);
    a.w = fmaf(s, w.w, a.w);
  }
  float* up = u + b * 1024 + threadIdx.x * 4;
  atomicAdd(up + 0, a.x);
  atomicAdd(up + 1, a.y);
  atomicAdd(up + 2, a.z);
  atomicAdd(up + 3, a.w);
}

// ---------- 4. fused GEMM: spart[ntile][r] = sum_{f in ntile} v[f]*tanh((A@W)[r,f]+u[b,f])
// Pipelined: buffer_load -> regs (coalesced 64B row-runs) -> ds_write to
// FRAGMENT-ORDER slots (reads conflict-free at lane*16), LDS double-buffer,
// one lgkm-only barrier per K-iter so global prefetch stays in flight.
// slot(row,kc) = (row>>4)*64 + kc*16 + (row&15); chunk c: row=c>>2, kc=c&3.
__global__ __launch_bounds__(256, 3) void gemm_score(const uint16_t* __restrict__ A,
                                                     const uint16_t* __restrict__ BT,
                                                     const float* __restrict__ u,
                                                     const float* __restrict__ v,
                                                     float* __restrict__ spart) {
  __shared__ uint4 sAB[2][1024];  // [buf][ A slots 0..511 | B slots 512..1023 ]
  __shared__ float sred[128];

  int bx = blockIdx.x;
  int g = bx >> 6, r = bx & 63;
  int mtile = g * 8 + (r & 7);
  int ntile = r >> 3;

  int tid = threadIdx.x;
  int lane = tid & 63;
  int wid  = tid >> 6;
  int wm = (wid & 1) * 64;
  int wn = (wid >> 1) * 64;
  int quad = lane >> 4, nib = lane & 15;

  f32x4 acc[4][4];
  #pragma unroll
  for (int i = 0; i < 4; ++i)
    #pragma unroll
    for (int j = 0; j < 4; ++j) acc[i][j] = (f32x4){0.f, 0.f, 0.f, 0.f};

  const int rowA = mtile * 128;
  const int rowB = ntile * 128;
  const int c0 = tid, c1 = tid + 256;            // global-order chunks
  // global base pointers (16B chunk: row=c>>2, kc=c&3); advance 4 uint4 per iter
  const uint4* pA0 = (const uint4*)(A  + (size_t)(rowA + (c0 >> 2)) * 1024 + (c0 & 3) * 8);
  const uint4* pA1 = (const uint4*)(A  + (size_t)(rowA + (c1 >> 2)) * 1024 + (c1 & 3) * 8);
  const uint4* pB0 = (const uint4*)(BT + (size_t)(rowB + (c0 >> 2)) * 1024 + (c0 & 3) * 8);
  const uint4* pB1 = (const uint4*)(BT + (size_t)(rowB + (c1 >> 2)) * 1024 + (c1 & 3) * 8);
  // fragment-order LDS slots
  const int s0 = ((c0 >> 6) << 6) | ((c0 & 3) << 4) | ((c0 >> 2) & 15);
  const int s1 = ((c1 >> 6) << 6) | ((c1 & 3) << 4) | ((c1 >> 2) & 15);

  uint4 ra0[2], ra1[2], rb0[2], rb1[2];  // ping-pong prefetch sets; set[j&1] holds iter j

  // preamble: load k=0 (set0) and k=1 (set1); write buf0 from set0
  ra0[0] = pA0[0]; ra1[0] = pA1[0]; rb0[0] = pB0[0]; rb1[0] = pB1[0];
  ra0[1] = pA0[4]; ra1[1] = pA1[4]; rb0[1] = pB0[4]; rb1[1] = pB1[4];
  sAB[0][s0] = ra0[0]; sAB[0][s1] = ra1[0];
  sAB[0][512 + s0] = rb0[0]; sAB[0][512 + s1] = rb1[0];
  barrier_lgkm();

  #pragma unroll 2
  for (int k = 0; k < 32; ++k) {
    const int cur = k & 1, nxt = cur ^ 1;
    if (k < 30) {  // prefetch iter k+2 into set[k&1] (freed by last iter's write)
      ra0[cur] = pA0[(k + 2) * 4]; ra1[cur] = pA1[(k + 2) * 4];
      rb0[cur] = pB0[(k + 2) * 4]; rb1[cur] = pB1[(k + 2) * 4];
    }
    bf16x8 af[4], bf[4];
    #pragma unroll
    for (int i = 0; i < 4; ++i)
      af[i] = *(const bf16x8*)&sAB[cur][((wm >> 4) + i) * 64 + lane];
    #pragma unroll
    for (int j = 0; j < 4; ++j)
      bf[j] = *(const bf16x8*)&sAB[cur][512 + ((wn >> 4) + j) * 64 + lane];

    #pragma unroll
    for (int i = 0; i < 4; ++i)
      #pragma unroll
      for (int j = 0; j < 4; ++j)
        acc[i][j] = __builtin_amdgcn_mfma_f32_16x16x32_bf16(af[i], bf[j], acc[i][j], 0, 0, 0);

    if (k < 31) {  // stage iter k+1 from set[(k+1)&1]
      sAB[nxt][s0] = ra0[nxt]; sAB[nxt][s1] = ra1[nxt];
      sAB[nxt][512 + s0] = rb0[nxt]; sAB[nxt][512 + s1] = rb1[nxt];
    }
    barrier_lgkm();
  }

  // ---- epilogue ----
  int b = rowA >> 11;  // 128 | 2048 so batch is block-uniform
  float vv[4], uu[4];
  #pragma unroll
  for (int j = 0; j < 4; ++j) {
    int col = ntile * 128 + wn + j * 16 + nib;
    vv[j] = v[col];
    uu[j] = u[b * 1024 + col];
  }
  float sloc[4][4];
  #pragma unroll
  for (int i = 0; i < 4; ++i) {
    #pragma unroll
    for (int reg = 0; reg < 4; ++reg) {
      float s = 0.f;
      #pragma unroll
      for (int j = 0; j < 4; ++j) s += vv[j] * tanh_fast(acc[i][j][reg] + uu[j]);
      s += __shfl_xor(s, 1);
      s += __shfl_xor(s, 2);
      s += __shfl_xor(s, 4);
      s += __shfl_xor(s, 8);
      sloc[i][reg] = s;  // row = wm + i*16 + quad*4 + reg, cols wn..wn+63
    }
  }
  if (wid < 2) {  // col-half 0 deposits
    if (nib == 0) {
      #pragma unroll
      for (int i = 0; i < 4; ++i)
        #pragma unroll
        for (int reg = 0; reg < 4; ++reg)
          sred[wm + i * 16 + quad * 4 + reg] = sloc[i][reg];
    }
  }
  __syncthreads();
  if (wid >= 2 && nib == 0) {  // col-half 1 combines + stores
    float* outp = spart + (size_t)ntile * 65536 + rowA;
    #pragma unroll
    for (int i = 0; i < 4; ++i) {
      int rloc = wm + i * 16 + quad * 4;
      float4 sv;
      #pragma unroll
      for (int reg = 0; reg < 4; ++reg)
        ((float*)&sv)[reg] = sloc[i][reg] + sred[rloc + reg];
      *(float4*)(outp + rloc) = sv;
    }
  }
}

// ---------- 5. softmax over t (2048) per batch; sums the 8 ntile partials ------
__global__ __launch_bounds__(256) void softmax_k(const float* __restrict__ spart,
                                                 float* __restrict__ wout) {
  int b = blockIdx.x, tid = threadIdx.x;
  __shared__ float red[4];
  float sv[8];
  float mx = -1e30f;
  #pragma unroll
  for (int i = 0; i < 8; ++i) {
    int idx = b * 2048 + i * 256 + tid;
    float s = 0.f;
    #pragma unroll
    for (int j = 0; j < 8; ++j) s += spart[j * 65536 + idx];
    sv[i] = s;
    mx = fmaxf(mx, s);
  }
  #pragma unroll
  for (int off = 1; off < 64; off <<= 1) mx = fmaxf(mx, __shfl_xor(mx, off));
  if ((tid & 63) == 0) red[tid >> 6] = mx;
  __syncthreads();
  mx = fmaxf(fmaxf(red[0], red[1]), fmaxf(red[2], red[3]));
  __syncthreads();
  float sum = 0.f;
  #pragma unroll
  for (int i = 0; i < 8; ++i) {
    sv[i] = __expf(sv[i] - mx);
    sum += sv[i];
  }
  #pragma unroll
  for (int off = 1; off < 64; off <<= 1) sum += __shfl_xor(sum, off);
  if ((tid & 63) == 0) red[tid >> 6] = sum;
  __syncthreads();
  float inv = 1.0f / (red[0] + red[1] + red[2] + red[3]);
  #pragma unroll
  for (int i = 0; i < 8; ++i) wout[b * 2048 + i * 256 + tid] = sv[i] * inv;
}

// ---------- 6. context[b,e] = sum_t w[b,t] * enc[b,t,e] ----------
__global__ __launch_bounds__(256) void context_k(const uint16_t* __restrict__ encA,
                                                 const float* __restrict__ w,
                                                 float* __restrict__ ctx) {
  int b = blockIdx.x >> 4, ch = blockIdx.x & 15;
  int t0 = ch * 128;
  __shared__ float lw[128];
  if (threadIdx.x < 128) lw[threadIdx.x] = w[b * 2048 + t0 + threadIdx.x];
  __syncthreads();
  int e0 = threadIdx.x * 4;
  float a0 = 0.f, a1 = 0.f, a2 = 0.f, a3 = 0.f;
  const uint16_t* base = encA + (size_t)b * 2048 * 1024 + (size_t)t0 * 1024 + e0;
  #pragma unroll 4
  for (int t = 0; t < 128; ++t) {
    uint2 p = *(const uint2*)(base + (size_t)t * 1024);
    float wt = lw[t];
    a0 = fmaf(wt, b2f_lo(p.x), a0);
    a1 = fmaf(wt, b2f_hi(p.x), a1);
    a2 = fmaf(wt, b2f_lo(p.y), a2);
    a3 = fmaf(wt, b2f_hi(p.y), a3);
  }
  atomicAdd(&ctx[b * 1024 + e0 + 0], a0);
  atomicAdd(&ctx[b * 1024 + e0 + 1], a1);
  atomicAdd(&ctx[b * 1024 + e0 + 2], a2);
  atomicAdd(&ctx[b * 1024 + e0 + 3], a3);
}

extern "C" void kernel_launch(void* const* d_in, const int* in_sizes, int n_in,
                              void* d_out, int out_size, void* d_ws, size_t ws_size,
                              hipStream_t stream) {
  const float* enc = (const float*)d_in[0];  // (32, 2048, 1024)
  const float* dec = (const float*)d_in[1];  // (32, 64, 1024)
  const float* Wa  = (const float*)d_in[2];  // (1024, 1024)
  const float* Ua  = (const float*)d_in[3];  // (1024, 1024)
  const float* Va  = (const float*)d_in[4];  // (1024, 1)

  float* out = (float*)d_out;
  float* ctx = out;                 // 32*1024
  float* wts = out + 32 * 1024;     // 32*2048*1

  char* ws = (char*)d_ws;
  uint16_t* encA  = (uint16_t*)ws;                           // 128 MB bf16 encoder
  uint16_t* WT    = (uint16_t*)(ws + 134217728);             // 2 MB bf16 W^T
  float*    ub    = (float*)  (ws + 136314880);              // 128 KB u[b,f]
  float*    spart = (float*)  (ws + 136445952);              // 2 MB score partials [8][65536]

  hipMemsetAsync(ctx, 0, 32 * 1024 * sizeof(float), stream);
  hipMemsetAsync(ub, 0, 32 * 1024 * sizeof(float), stream);

  convert_enc<<<32768, 256, 0, stream>>>((const float4*)enc, (uint4*)encA);
  convert_WT<<<256, 256, 0, stream>>>(Wa, WT);
  compute_u<<<256, 256, 0, stream>>>(dec, (const float4*)Ua, ub);
  gemm_score<<<4096, 256, 0, stream>>>(encA, WT, ub, Va, spart);
  softmax_k<<<32, 256, 0, stream>>>(spart, wts);
  context_k<<<512, 256, 0, stream>>>(encA, wts, ctx);
}

// Round 5
// 620.075 us; speedup vs baseline: 1.9043x; 1.9043x over previous
//
#include <hip/hip_runtime.h>
#include <stdint.h>

typedef __attribute__((ext_vector_type(8))) __bf16 bf16x8;
typedef __attribute__((ext_vector_type(4))) float  f32x4;

// ---------- helpers ----------
__device__ __forceinline__ uint16_t f2b(float f) {           // fp32 -> bf16 RNE
  uint32_t u = __float_as_uint(f);
  u += 0x7fffu + ((u >> 16) & 1u);
  return (uint16_t)(u >> 16);
}
__device__ __forceinline__ float b2f_lo(uint32_t p) { return __uint_as_float(p << 16); }
__device__ __forceinline__ float b2f_hi(uint32_t p) { return __uint_as_float(p & 0xffff0000u); }

// branch-free tanh: 1 - 2/(e^{2x}+1); saturates correctly at +-1
__device__ __forceinline__ float tanh_fast(float x) {
  float e = __expf(2.0f * x);
  return 1.0f - 2.0f / (e + 1.0f);
}

// barrier draining ONLY lgkmcnt (ds ops) — global prefetch stays in flight.
__device__ __forceinline__ void barrier_lgkm() {
  asm volatile("s_waitcnt lgkmcnt(0)\n\ts_barrier" ::: "memory");
}

// ---------- 1. encoder fp32 -> bf16 (8 elems/thread) ----------
__global__ __launch_bounds__(256) void convert_enc(const float4* __restrict__ in,
                                                   uint4* __restrict__ out) {
  int i = blockIdx.x * 256 + threadIdx.x;
  float4 a = in[2 * i], b = in[2 * i + 1];
  uint4 o;
  o.x = (uint32_t)f2b(a.x) | ((uint32_t)f2b(a.y) << 16);
  o.y = (uint32_t)f2b(a.z) | ((uint32_t)f2b(a.w) << 16);
  o.z = (uint32_t)f2b(b.x) | ((uint32_t)f2b(b.y) << 16);
  o.w = (uint32_t)f2b(b.z) | ((uint32_t)f2b(b.w) << 16);
  out[i] = o;
}

// ---------- 2. W_a (K x N) -> WT bf16 (N x K), LDS-tiled transpose ----------
__global__ __launch_bounds__(256) void convert_WT(const float* __restrict__ W,
                                                  uint16_t* __restrict__ WT) {
  __shared__ float tile[64][65];
  int k0 = (blockIdx.x & 15) * 64;
  int n0 = (blockIdx.x >> 4) * 64;
  #pragma unroll
  for (int it = 0; it < 16; ++it) {
    int idx = it * 256 + threadIdx.x;
    int kr = idx >> 6, nc = idx & 63;
    tile[kr][nc] = W[(size_t)(k0 + kr) * 1024 + n0 + nc];
  }
  __syncthreads();
  #pragma unroll
  for (int it = 0; it < 16; ++it) {
    int idx = it * 256 + threadIdx.x;
    int nr = idx >> 6, kc = idx & 63;
    WT[(size_t)(n0 + nr) * 1024 + k0 + kc] = f2b(tile[kc][nr]);
  }
}

// ---------- 3. u[b,f] += sum_{d in seg} dec_last[b,d] * U[d,f]  (fp32, atomic) ----
__global__ __launch_bounds__(256) void compute_u(const float* __restrict__ dec,
                                                 const float4* __restrict__ U4,
                                                 float* __restrict__ u) {
  int b = blockIdx.x >> 3, dseg = blockIdx.x & 7;
  __shared__ float sdec[128];
  if (threadIdx.x < 128)
    sdec[threadIdx.x] = dec[(size_t)b * 64 * 1024 + 63 * 1024 + dseg * 128 + threadIdx.x];
  __syncthreads();
  float4 a = {0.f, 0.f, 0.f, 0.f};
  const float4* Ub = U4 + (size_t)dseg * 128 * 256 + threadIdx.x;
  #pragma unroll 4
  for (int d = 0; d < 128; ++d) {
    float4 w = Ub[(size_t)d * 256];
    float s = sdec[d];
    a.x = fmaf(s, w.x, a.x);
    a.y = fmaf(s, w.y, a.y);
    a.z = fmaf(s, w.z, a.z);
    a.w = fmaf(s, w.w, a.w);
  }
  float* up = u + b * 1024 + threadIdx.x * 4;
  atomicAdd(up + 0, a.x);
  atomicAdd(up + 1, a.y);
  atomicAdd(up + 2, a.z);
  atomicAdd(up + 3, a.w);
}

// ---------- 4. fused GEMM: spart[ntile][r] = sum_{f in ntile} v[f]*tanh((A@W)[r,f]+u[b,f])
// Pipelined, MANUALLY unrolled x2 (R4 regression: runtime-indexed prefetch
// arrays went to scratch -> 2 GB spill traffic; all regs are named scalars now).
// buffer_load -> regs (coalesced 64B row-runs) -> ds_write to FRAGMENT-ORDER
// slots (reads conflict-free at lane*16), LDS double-buffer, lgkm-only barrier.
// slot(row,kc) = (row>>4)*64 + kc*16 + (row&15); chunk c: row=c>>2, kc=c&3.
__global__ __launch_bounds__(256, 3) void gemm_score(const uint16_t* __restrict__ A,
                                                     const uint16_t* __restrict__ BT,
                                                     const float* __restrict__ u,
                                                     const float* __restrict__ v,
                                                     float* __restrict__ spart) {
  __shared__ uint4 sAB[2][1024];  // [buf][ A slots 0..511 | B slots 512..1023 ]
  __shared__ float sred[128];

  int bx = blockIdx.x;
  int g = bx >> 6, r = bx & 63;
  int mtile = g * 8 + (r & 7);
  int ntile = r >> 3;

  int tid = threadIdx.x;
  int lane = tid & 63;
  int wid  = tid >> 6;
  int wm = (wid & 1) * 64;
  int wn = (wid >> 1) * 64;
  int quad = lane >> 4, nib = lane & 15;

  f32x4 acc[4][4];
  #pragma unroll
  for (int i = 0; i < 4; ++i)
    #pragma unroll
    for (int j = 0; j < 4; ++j) acc[i][j] = (f32x4){0.f, 0.f, 0.f, 0.f};

  const int rowA = mtile * 128;
  const int rowB = ntile * 128;
  const int c0 = tid, c1 = tid + 256;            // global-order chunks
  // global base pointers (16B chunk: row=c>>2, kc=c&3); +4 uint4 per K-iter
  const uint4* pA0 = (const uint4*)(A  + (size_t)(rowA + (c0 >> 2)) * 1024 + (c0 & 3) * 8);
  const uint4* pA1 = (const uint4*)(A  + (size_t)(rowA + (c1 >> 2)) * 1024 + (c1 & 3) * 8);
  const uint4* pB0 = (const uint4*)(BT + (size_t)(rowB + (c0 >> 2)) * 1024 + (c0 & 3) * 8);
  const uint4* pB1 = (const uint4*)(BT + (size_t)(rowB + (c1 >> 2)) * 1024 + (c1 & 3) * 8);
  // fragment-order LDS slots
  const int s0 = ((c0 >> 6) << 6) | ((c0 & 3) << 4) | ((c0 >> 2) & 15);
  const int s1 = ((c1 >> 6) << 6) | ((c1 & 3) << 4) | ((c1 >> 2) & 15);

  // named prefetch sets (NO arrays): set-a holds even iters, set-b odd iters
  uint4 A0a, A1a, B0a, B1a, A0b, A1b, B0b, B1b;

#define GEMM_STEP(BUF)                                                          \
  do {                                                                          \
    bf16x8 af[4], bf[4];                                                        \
    _Pragma("unroll")                                                           \
    for (int i = 0; i < 4; ++i)                                                 \
      af[i] = *(const bf16x8*)&sAB[BUF][((wm >> 4) + i) * 64 + lane];           \
    _Pragma("unroll")                                                           \
    for (int j = 0; j < 4; ++j)                                                 \
      bf[j] = *(const bf16x8*)&sAB[BUF][512 + ((wn >> 4) + j) * 64 + lane];     \
    _Pragma("unroll")                                                           \
    for (int i = 0; i < 4; ++i)                                                 \
      _Pragma("unroll")                                                         \
      for (int j = 0; j < 4; ++j)                                               \
        acc[i][j] = __builtin_amdgcn_mfma_f32_16x16x32_bf16(af[i], bf[j],       \
                                                            acc[i][j], 0, 0, 0);\
  } while (0)

  // preamble: k=0 -> set-a, k=1 -> set-b; stage k=0 into buf0
  A0a = pA0[0]; A1a = pA1[0]; B0a = pB0[0]; B1a = pB1[0];
  A0b = pA0[4]; A1b = pA1[4]; B0b = pB0[4]; B1b = pB1[4];
  sAB[0][s0] = A0a; sAB[0][s1] = A1a;
  sAB[0][512 + s0] = B0a; sAB[0][512 + s1] = B1a;
  barrier_lgkm();

  for (int k = 0; k < 32; k += 2) {
    // ---- even body: compute from buf0; set-a free (staged last odd body)
    if (k < 30) {
      A0a = pA0[(k + 2) * 4]; A1a = pA1[(k + 2) * 4];
      B0a = pB0[(k + 2) * 4]; B1a = pB1[(k + 2) * 4];
    }
    GEMM_STEP(0);
    // stage iter k+1 (set-b) into buf1
    sAB[1][s0] = A0b; sAB[1][s1] = A1b;
    sAB[1][512 + s0] = B0b; sAB[1][512 + s1] = B1b;
    barrier_lgkm();

    // ---- odd body: compute from buf1; set-b free
    if (k < 29) {
      A0b = pA0[(k + 3) * 4]; A1b = pA1[(k + 3) * 4];
      B0b = pB0[(k + 3) * 4]; B1b = pB1[(k + 3) * 4];
    }
    GEMM_STEP(1);
    if (k < 30) {  // stage iter k+2 (set-a) into buf0
      sAB[0][s0] = A0a; sAB[0][s1] = A1a;
      sAB[0][512 + s0] = B0a; sAB[0][512 + s1] = B1a;
    }
    barrier_lgkm();
  }
#undef GEMM_STEP

  // ---- epilogue ----
  int b = rowA >> 11;  // 128 | 2048 so batch is block-uniform
  float vv[4], uu[4];
  #pragma unroll
  for (int j = 0; j < 4; ++j) {
    int col = ntile * 128 + wn + j * 16 + nib;
    vv[j] = v[col];
    uu[j] = u[b * 1024 + col];
  }
  float sloc[4][4];
  #pragma unroll
  for (int i = 0; i < 4; ++i) {
    #pragma unroll
    for (int reg = 0; reg < 4; ++reg) {
      float s = 0.f;
      #pragma unroll
      for (int j = 0; j < 4; ++j) s += vv[j] * tanh_fast(acc[i][j][reg] + uu[j]);
      s += __shfl_xor(s, 1);
      s += __shfl_xor(s, 2);
      s += __shfl_xor(s, 4);
      s += __shfl_xor(s, 8);
      sloc[i][reg] = s;  // row = wm + i*16 + quad*4 + reg, cols wn..wn+63
    }
  }
  if (wid < 2 && nib == 0) {  // col-half 0 deposits
    #pragma unroll
    for (int i = 0; i < 4; ++i)
      #pragma unroll
      for (int reg = 0; reg < 4; ++reg)
        sred[wm + i * 16 + quad * 4 + reg] = sloc[i][reg];
  }
  __syncthreads();
  if (wid >= 2 && nib == 0) {  // col-half 1 combines + stores
    float* outp = spart + (size_t)ntile * 65536 + rowA;
    #pragma unroll
    for (int i = 0; i < 4; ++i) {
      int rloc = wm + i * 16 + quad * 4;
      float4 sv;
      #pragma unroll
      for (int reg = 0; reg < 4; ++reg)
        ((float*)&sv)[reg] = sloc[i][reg] + sred[rloc + reg];
      *(float4*)(outp + rloc) = sv;
    }
  }
}

// ---------- 5. softmax over t (2048) per batch; sums the 8 ntile partials ------
__global__ __launch_bounds__(256) void softmax_k(const float* __restrict__ spart,
                                                 float* __restrict__ wout) {
  int b = blockIdx.x, tid = threadIdx.x;
  __shared__ float red[4];
  float sv[8];
  float mx = -1e30f;
  #pragma unroll
  for (int i = 0; i < 8; ++i) {
    int idx = b * 2048 + i * 256 + tid;
    float s = 0.f;
    #pragma unroll
    for (int j = 0; j < 8; ++j) s += spart[j * 65536 + idx];
    sv[i] = s;
    mx = fmaxf(mx, s);
  }
  #pragma unroll
  for (int off = 1; off < 64; off <<= 1) mx = fmaxf(mx, __shfl_xor(mx, off));
  if ((tid & 63) == 0) red[tid >> 6] = mx;
  __syncthreads();
  mx = fmaxf(fmaxf(red[0], red[1]), fmaxf(red[2], red[3]));
  __syncthreads();
  float sum = 0.f;
  #pragma unroll
  for (int i = 0; i < 8; ++i) {
    sv[i] = __expf(sv[i] - mx);
    sum += sv[i];
  }
  #pragma unroll
  for (int off = 1; off < 64; off <<= 1) sum += __shfl_xor(sum, off);
  if ((tid & 63) == 0) red[tid >> 6] = sum;
  __syncthreads();
  float inv = 1.0f / (red[0] + red[1] + red[2] + red[3]);
  #pragma unroll
  for (int i = 0; i < 8; ++i) wout[b * 2048 + i * 256 + tid] = sv[i] * inv;
}

// ---------- 6. context[b,e] = sum_t w[b,t] * enc[b,t,e] ----------
__global__ __launch_bounds__(256) void context_k(const uint16_t* __restrict__ encA,
                                                 const float* __restrict__ w,
                                                 float* __restrict__ ctx) {
  int b = blockIdx.x >> 4, ch = blockIdx.x & 15;
  int t0 = ch * 128;
  __shared__ float lw[128];
  if (threadIdx.x < 128) lw[threadIdx.x] = w[b * 2048 + t0 + threadIdx.x];
  __syncthreads();
  int e0 = threadIdx.x * 4;
  float a0 = 0.f, a1 = 0.f, a2 = 0.f, a3 = 0.f;
  const uint16_t* base = encA + (size_t)b * 2048 * 1024 + (size_t)t0 * 1024 + e0;
  #pragma unroll 4
  for (int t = 0; t < 128; ++t) {
    uint2 p = *(const uint2*)(base + (size_t)t * 1024);
    float wt = lw[t];
    a0 = fmaf(wt, b2f_lo(p.x), a0);
    a1 = fmaf(wt, b2f_hi(p.x), a1);
    a2 = fmaf(wt, b2f_lo(p.y), a2);
    a3 = fmaf(wt, b2f_hi(p.y), a3);
  }
  atomicAdd(&ctx[b * 1024 + e0 + 0], a0);
  atomicAdd(&ctx[b * 1024 + e0 + 1], a1);
  atomicAdd(&ctx[b * 1024 + e0 + 2], a2);
  atomicAdd(&ctx[b * 1024 + e0 + 3], a3);
}

extern "C" void kernel_launch(void* const* d_in, const int* in_sizes, int n_in,
                              void* d_out, int out_size, void* d_ws, size_t ws_size,
                              hipStream_t stream) {
  const float* enc = (const float*)d_in[0];  // (32, 2048, 1024)
  const float* dec = (const float*)d_in[1];  // (32, 64, 1024)
  const float* Wa  = (const float*)d_in[2];  // (1024, 1024)
  const float* Ua  = (const float*)d_in[3];  // (1024, 1024)
  const float* Va  = (const float*)d_in[4];  // (1024, 1)

  float* out = (float*)d_out;
  float* ctx = out;                 // 32*1024
  float* wts = out + 32 * 1024;     // 32*2048*1

  char* ws = (char*)d_ws;
  uint16_t* encA  = (uint16_t*)ws;                           // 128 MB bf16 encoder
  uint16_t* WT    = (uint16_t*)(ws + 134217728);             // 2 MB bf16 W^T
  float*    ub    = (float*)  (ws + 136314880);              // 128 KB u[b,f]
  float*    spart = (float*)  (ws + 136445952);              // 2 MB score partials [8][65536]

  hipMemsetAsync(ctx, 0, 32 * 1024 * sizeof(float), stream);
  hipMemsetAsync(ub, 0, 32 * 1024 * sizeof(float), stream);

  convert_enc<<<32768, 256, 0, stream>>>((const float4*)enc, (uint4*)encA);
  convert_WT<<<256, 256, 0, stream>>>(Wa, WT);
  compute_u<<<256, 256, 0, stream>>>(dec, (const float4*)Ua, ub);
  gemm_score<<<4096, 256, 0, stream>>>(encA, WT, ub, Va, spart);
  softmax_k<<<32, 256, 0, stream>>>(spart, wts);
  context_k<<<512, 256, 0, stream>>>(encA, wts, ctx);
}

// Round 6
// 600.001 us; speedup vs baseline: 1.9681x; 1.0335x over previous
//
#include <hip/hip_runtime.h>
#include <stdint.h>

typedef __attribute__((ext_vector_type(8))) __bf16 bf16x8;
typedef __attribute__((ext_vector_type(4))) float  f32x4;

// ---------- helpers ----------
__device__ __forceinline__ uint16_t f2b(float f) {           // fp32 -> bf16 RNE
  uint32_t u = __float_as_uint(f);
  u += 0x7fffu + ((u >> 16) & 1u);
  return (uint16_t)(u >> 16);
}
__device__ __forceinline__ float b2f_lo(uint32_t p) { return __uint_as_float(p << 16); }
__device__ __forceinline__ float b2f_hi(uint32_t p) { return __uint_as_float(p & 0xffff0000u); }

// branch-free tanh: 1 - 2/(e^{2x}+1); saturates correctly at +-1
__device__ __forceinline__ float tanh_fast(float x) {
  float e = __expf(2.0f * x);
  return 1.0f - 2.0f / (e + 1.0f);
}

// barrier draining ONLY lgkmcnt (ds ops) — global prefetch stays in flight.
__device__ __forceinline__ void barrier_lgkm() {
  asm volatile("s_waitcnt lgkmcnt(0)\n\ts_barrier" ::: "memory");
}

// ---------- 1. encoder fp32 -> bf16 (8 elems/thread) ----------
__global__ __launch_bounds__(256) void convert_enc(const float4* __restrict__ in,
                                                   uint4* __restrict__ out) {
  int i = blockIdx.x * 256 + threadIdx.x;
  float4 a = in[2 * i], b = in[2 * i + 1];
  uint4 o;
  o.x = (uint32_t)f2b(a.x) | ((uint32_t)f2b(a.y) << 16);
  o.y = (uint32_t)f2b(a.z) | ((uint32_t)f2b(a.w) << 16);
  o.z = (uint32_t)f2b(b.x) | ((uint32_t)f2b(b.y) << 16);
  o.w = (uint32_t)f2b(b.z) | ((uint32_t)f2b(b.w) << 16);
  out[i] = o;
}

// ---------- 2. W_a (K x N) -> WT bf16 (N x K), LDS-tiled transpose ----------
__global__ __launch_bounds__(256) void convert_WT(const float* __restrict__ W,
                                                  uint16_t* __restrict__ WT) {
  __shared__ float tile[64][65];
  int k0 = (blockIdx.x & 15) * 64;
  int n0 = (blockIdx.x >> 4) * 64;
  #pragma unroll
  for (int it = 0; it < 16; ++it) {
    int idx = it * 256 + threadIdx.x;
    int kr = idx >> 6, nc = idx & 63;
    tile[kr][nc] = W[(size_t)(k0 + kr) * 1024 + n0 + nc];
  }
  __syncthreads();
  #pragma unroll
  for (int it = 0; it < 16; ++it) {
    int idx = it * 256 + threadIdx.x;
    int nr = idx >> 6, kc = idx & 63;
    WT[(size_t)(n0 + nr) * 1024 + k0 + kc] = f2b(tile[kc][nr]);
  }
}

// ---------- 3. u[b,f] += sum_{d in seg} dec_last[b,d] * U[d,f]  (fp32, atomic) ----
__global__ __launch_bounds__(256) void compute_u(const float* __restrict__ dec,
                                                 const float4* __restrict__ U4,
                                                 float* __restrict__ u) {
  int b = blockIdx.x >> 3, dseg = blockIdx.x & 7;
  __shared__ float sdec[128];
  if (threadIdx.x < 128)
    sdec[threadIdx.x] = dec[(size_t)b * 64 * 1024 + 63 * 1024 + dseg * 128 + threadIdx.x];
  __syncthreads();
  float4 a = {0.f, 0.f, 0.f, 0.f};
  const float4* Ub = U4 + (size_t)dseg * 128 * 256 + threadIdx.x;
  #pragma unroll 4
  for (int d = 0; d < 128; ++d) {
    float4 w = Ub[(size_t)d * 256];
    float s = sdec[d];
    a.x = fmaf(s, w.x, a.x);
    a.y = fmaf(s, w.y, a.y);
    a.z = fmaf(s, w.z, a.z);
    a.w = fmaf(s, w.w, a.w);
  }
  float* up = u + b * 1024 + threadIdx.x * 4;
  atomicAdd(up + 0, a.x);
  atomicAdd(up + 1, a.y);
  atomicAdd(up + 2, a.z);
  atomicAdd(up + 3, a.w);
}

// ---------- 4. fused GEMM: spart[ntile][r] = sum_{f in ntile} v[f]*tanh((A@W)[r,f]+u[b,f])
// Pipelined, manually unrolled x2, named prefetch regs (R4 lesson: no runtime-
// indexed arrays). buffer_load -> regs -> ds_write, LDS double-buffer, lgkm-only
// barrier. LDS slots are fragment-order WITH XOR SWIZZLE (R5 lesson: raw
// fragment-order makes ds_write 4-way bank-conflicted, 5e7 cyc/dispatch):
//   slot(row,kc) = [ (row>>4)*64 + kc*16 + (row&15) ] ^ (kc<<1)
// write: lanes' slot mod 8 now spread over all banks (verified per 8-lane phase);
// read: lane L reads X*64 + (L ^ ((L>>4)<<1)) — bijective within 16-slot group,
// still conflict-free.
__global__ __launch_bounds__(256, 3) void gemm_score(const uint16_t* __restrict__ A,
                                                     const uint16_t* __restrict__ BT,
                                                     const float* __restrict__ u,
                                                     const float* __restrict__ v,
                                                     float* __restrict__ spart) {
  __shared__ uint4 sAB[2][1024];  // [buf][ A slots 0..511 | B slots 512..1023 ]
  __shared__ float sred[128];

  int bx = blockIdx.x;
  int g = bx >> 6, r = bx & 63;
  int mtile = g * 8 + (r & 7);
  int ntile = r >> 3;

  int tid = threadIdx.x;
  int lane = tid & 63;
  int wid  = tid >> 6;
  int wm = (wid & 1) * 64;
  int wn = (wid >> 1) * 64;
  int quad = lane >> 4, nib = lane & 15;
  const int lsw = lane ^ ((lane >> 4) << 1);  // swizzled read lane

  f32x4 acc[4][4];
  #pragma unroll
  for (int i = 0; i < 4; ++i)
    #pragma unroll
    for (int j = 0; j < 4; ++j) acc[i][j] = (f32x4){0.f, 0.f, 0.f, 0.f};

  const int rowA = mtile * 128;
  const int rowB = ntile * 128;
  const int c0 = tid, c1 = tid + 256;            // global-order chunks
  // global base pointers (16B chunk: row=c>>2, kc=c&3); +4 uint4 per K-iter
  const uint4* pA0 = (const uint4*)(A  + (size_t)(rowA + (c0 >> 2)) * 1024 + (c0 & 3) * 8);
  const uint4* pA1 = (const uint4*)(A  + (size_t)(rowA + (c1 >> 2)) * 1024 + (c1 & 3) * 8);
  const uint4* pB0 = (const uint4*)(BT + (size_t)(rowB + (c0 >> 2)) * 1024 + (c0 & 3) * 8);
  const uint4* pB1 = (const uint4*)(BT + (size_t)(rowB + (c1 >> 2)) * 1024 + (c1 & 3) * 8);
  // fragment-order LDS slots, XOR-swizzled by kc (kc = c&3, same for c0,c1)
  const int s0 = (((c0 >> 6) << 6) | ((c0 & 3) << 4) | ((c0 >> 2) & 15)) ^ ((c0 & 3) << 1);
  const int s1 = (((c1 >> 6) << 6) | ((c1 & 3) << 4) | ((c1 >> 2) & 15)) ^ ((c1 & 3) << 1);

  // named prefetch sets (NO arrays): set-a holds even iters, set-b odd iters
  uint4 A0a, A1a, B0a, B1a, A0b, A1b, B0b, B1b;

#define GEMM_STEP(BUF)                                                          \
  do {                                                                          \
    bf16x8 af[4], bf[4];                                                        \
    _Pragma("unroll")                                                           \
    for (int i = 0; i < 4; ++i)                                                 \
      af[i] = *(const bf16x8*)&sAB[BUF][((wm >> 4) + i) * 64 + lsw];            \
    _Pragma("unroll")                                                           \
    for (int j = 0; j < 4; ++j)                                                 \
      bf[j] = *(const bf16x8*)&sAB[BUF][512 + ((wn >> 4) + j) * 64 + lsw];      \
    _Pragma("unroll")                                                           \
    for (int i = 0; i < 4; ++i)                                                 \
      _Pragma("unroll")                                                         \
      for (int j = 0; j < 4; ++j)                                               \
        acc[i][j] = __builtin_amdgcn_mfma_f32_16x16x32_bf16(af[i], bf[j],       \
                                                            acc[i][j], 0, 0, 0);\
  } while (0)

  // preamble: k=0 -> set-a, k=1 -> set-b; stage k=0 into buf0
  A0a = pA0[0]; A1a = pA1[0]; B0a = pB0[0]; B1a = pB1[0];
  A0b = pA0[4]; A1b = pA1[4]; B0b = pB0[4]; B1b = pB1[4];
  sAB[0][s0] = A0a; sAB[0][s1] = A1a;
  sAB[0][512 + s0] = B0a; sAB[0][512 + s1] = B1a;
  barrier_lgkm();

  for (int k = 0; k < 32; k += 2) {
    // ---- even body: compute from buf0; set-a free (staged last odd body)
    if (k < 30) {
      A0a = pA0[(k + 2) * 4]; A1a = pA1[(k + 2) * 4];
      B0a = pB0[(k + 2) * 4]; B1a = pB1[(k + 2) * 4];
    }
    GEMM_STEP(0);
    // stage iter k+1 (set-b) into buf1
    sAB[1][s0] = A0b; sAB[1][s1] = A1b;
    sAB[1][512 + s0] = B0b; sAB[1][512 + s1] = B1b;
    barrier_lgkm();

    // ---- odd body: compute from buf1; set-b free
    if (k < 29) {
      A0b = pA0[(k + 3) * 4]; A1b = pA1[(k + 3) * 4];
      B0b = pB0[(k + 3) * 4]; B1b = pB1[(k + 3) * 4];
    }
    GEMM_STEP(1);
    if (k < 30) {  // stage iter k+2 (set-a) into buf0
      sAB[0][s0] = A0a; sAB[0][s1] = A1a;
      sAB[0][512 + s0] = B0a; sAB[0][512 + s1] = B1a;
    }
    barrier_lgkm();
  }
#undef GEMM_STEP

  // ---- epilogue ----
  int b = rowA >> 11;  // 128 | 2048 so batch is block-uniform
  float vv[4], uu[4];
  #pragma unroll
  for (int j = 0; j < 4; ++j) {
    int col = ntile * 128 + wn + j * 16 + nib;
    vv[j] = v[col];
    uu[j] = u[b * 1024 + col];
  }
  float sloc[4][4];
  #pragma unroll
  for (int i = 0; i < 4; ++i) {
    #pragma unroll
    for (int reg = 0; reg < 4; ++reg) {
      float s = 0.f;
      #pragma unroll
      for (int j = 0; j < 4; ++j) s += vv[j] * tanh_fast(acc[i][j][reg] + uu[j]);
      s += __shfl_xor(s, 1);
      s += __shfl_xor(s, 2);
      s += __shfl_xor(s, 4);
      s += __shfl_xor(s, 8);
      sloc[i][reg] = s;  // row = wm + i*16 + quad*4 + reg, cols wn..wn+63
    }
  }
  if (wid < 2 && nib == 0) {  // col-half 0 deposits
    #pragma unroll
    for (int i = 0; i < 4; ++i)
      #pragma unroll
      for (int reg = 0; reg < 4; ++reg)
        sred[wm + i * 16 + quad * 4 + reg] = sloc[i][reg];
  }
  __syncthreads();
  if (wid >= 2 && nib == 0) {  // col-half 1 combines + stores
    float* outp = spart + (size_t)ntile * 65536 + rowA;
    #pragma unroll
    for (int i = 0; i < 4; ++i) {
      int rloc = wm + i * 16 + quad * 4;
      float4 sv;
      #pragma unroll
      for (int reg = 0; reg < 4; ++reg)
        ((float*)&sv)[reg] = sloc[i][reg] + sred[rloc + reg];
      *(float4*)(outp + rloc) = sv;
    }
  }
}

// ---------- 5. softmax over t (2048) per batch; sums the 8 ntile partials ------
__global__ __launch_bounds__(256) void softmax_k(const float* __restrict__ spart,
                                                 float* __restrict__ wout) {
  int b = blockIdx.x, tid = threadIdx.x;
  __shared__ float red[4];
  float sv[8];
  float mx = -1e30f;
  #pragma unroll
  for (int i = 0; i < 8; ++i) {
    int idx = b * 2048 + i * 256 + tid;
    float s = 0.f;
    #pragma unroll
    for (int j = 0; j < 8; ++j) s += spart[j * 65536 + idx];
    sv[i] = s;
    mx = fmaxf(mx, s);
  }
  #pragma unroll
  for (int off = 1; off < 64; off <<= 1) mx = fmaxf(mx, __shfl_xor(mx, off));
  if ((tid & 63) == 0) red[tid >> 6] = mx;
  __syncthreads();
  mx = fmaxf(fmaxf(red[0], red[1]), fmaxf(red[2], red[3]));
  __syncthreads();
  float sum = 0.f;
  #pragma unroll
  for (int i = 0; i < 8; ++i) {
    sv[i] = __expf(sv[i] - mx);
    sum += sv[i];
  }
  #pragma unroll
  for (int off = 1; off < 64; off <<= 1) sum += __shfl_xor(sum, off);
  if ((tid & 63) == 0) red[tid >> 6] = sum;
  __syncthreads();
  float inv = 1.0f / (red[0] + red[1] + red[2] + red[3]);
  #pragma unroll
  for (int i = 0; i < 8; ++i) wout[b * 2048 + i * 256 + tid] = sv[i] * inv;
}

// ---------- 6. context[b,e] = sum_t w[b,t] * enc[b,t,e]; 32 t-chunks of 64 ----
__global__ __launch_bounds__(256) void context_k(const uint16_t* __restrict__ encA,
                                                 const float* __restrict__ w,
                                                 float* __restrict__ ctx) {
  int b = blockIdx.x >> 5, ch = blockIdx.x & 31;
  int t0 = ch * 64;
  __shared__ float lw[64];
  if (threadIdx.x < 64) lw[threadIdx.x] = w[b * 2048 + t0 + threadIdx.x];
  __syncthreads();
  int e0 = threadIdx.x * 4;
  float a0 = 0.f, a1 = 0.f, a2 = 0.f, a3 = 0.f;
  const uint16_t* base = encA + (size_t)b * 2048 * 1024 + (size_t)t0 * 1024 + e0;
  #pragma unroll 4
  for (int t = 0; t < 64; ++t) {
    uint2 p = *(const uint2*)(base + (size_t)t * 1024);
    float wt = lw[t];
    a0 = fmaf(wt, b2f_lo(p.x), a0);
    a1 = fmaf(wt, b2f_hi(p.x), a1);
    a2 = fmaf(wt, b2f_lo(p.y), a2);
    a3 = fmaf(wt, b2f_hi(p.y), a3);
  }
  atomicAdd(&ctx[b * 1024 + e0 + 0], a0);
  atomicAdd(&ctx[b * 1024 + e0 + 1], a1);
  atomicAdd(&ctx[b * 1024 + e0 + 2], a2);
  atomicAdd(&ctx[b * 1024 + e0 + 3], a3);
}

extern "C" void kernel_launch(void* const* d_in, const int* in_sizes, int n_in,
                              void* d_out, int out_size, void* d_ws, size_t ws_size,
                              hipStream_t stream) {
  const float* enc = (const float*)d_in[0];  // (32, 2048, 1024)
  const float* dec = (const float*)d_in[1];  // (32, 64, 1024)
  const float* Wa  = (const float*)d_in[2];  // (1024, 1024)
  const float* Ua  = (const float*)d_in[3];  // (1024, 1024)
  const float* Va  = (const float*)d_in[4];  // (1024, 1)

  float* out = (float*)d_out;
  float* ctx = out;                 // 32*1024
  float* wts = out + 32 * 1024;     // 32*2048*1

  char* ws = (char*)d_ws;
  uint16_t* encA  = (uint16_t*)ws;                           // 128 MB bf16 encoder
  uint16_t* WT    = (uint16_t*)(ws + 134217728);             // 2 MB bf16 W^T
  float*    ub    = (float*)  (ws + 136314880);              // 128 KB u[b,f]
  float*    spart = (float*)  (ws + 136445952);              // 2 MB score partials [8][65536]

  hipMemsetAsync(ctx, 0, 32 * 1024 * sizeof(float), stream);
  hipMemsetAsync(ub, 0, 32 * 1024 * sizeof(float), stream);

  convert_enc<<<32768, 256, 0, stream>>>((const float4*)enc, (uint4*)encA);
  convert_WT<<<256, 256, 0, stream>>>(Wa, WT);
  compute_u<<<256, 256, 0, stream>>>(dec, (const float4*)Ua, ub);
  gemm_score<<<4096, 256, 0, stream>>>(encA, WT, ub, Va, spart);
  softmax_k<<<32, 256, 0, stream>>>(spart, wts);
  context_k<<<1024, 256, 0, stream>>>(encA, wts, ctx);
}